// Round 4
// baseline (42.130 us; speedup 1.0000x reference)
//
#include <hip/hip_runtime.h>
#include <math.h>

#define H      4096
#define NH     32
#define NKV    8
#define HD     128
#define CACHE  2048
#define GROUPS (NH / NKV)
#define CHUNK  32                      // positions per attention block
#define NSPL   (CACHE / CHUNK)         // max splits = 64
#define KSTR   132                     // LDS row stride (floats)
#define SCALE  0.08838834764831845f    // 1/sqrt(128)

// workspace layout (floats) — qkv partials are split-K=2: [half][rows]
#define QOFF 0                         // q partials [2][4096]
#define KOFF 8192                      // k partials [2][1024]
#define VOFF 10240                     // v partials [2][1024]
#define POFF 12288                     // attn partials: [NH][NSPL]{m,l,pad,pad,acc[128]}
#define PSTRIDE 132
#define CTXOFF (POFF + NH * NSPL * PSTRIDE)   // ctx[4096]

// ------------- QKV GEMV: split-K=2, no LDS, streaming; item = (half, row) -------------
__global__ __launch_bounds__(256, 4) void qkv_gemv(
    const float* __restrict__ x,
    const float* __restrict__ qw, const float* __restrict__ kw,
    const float* __restrict__ vw, float* __restrict__ ws) {
  const int t    = threadIdx.x;
  const int wave = t >> 6;
  const int lane = t & 63;
  const int item = blockIdx.x * 4 + wave;        // 0..12287
  const int half = item >> 12 >> 1 ? 1 : (item >= 6144);   // item/6144
  const int row  = (half == 0) ? item : item - 6144;

  const float* w;
  float* outp;
  int r;
  if (row < 4096)      { w = qw; r = row;        outp = ws + QOFF + half * 4096; }
  else if (row < 5120) { w = kw; r = row - 4096; outp = ws + KOFF + half * 1024; }
  else                 { w = vw; r = row - 5120; outp = ws + VOFF + half * 1024; }

  const float4* wr = (const float4*)(w + (size_t)r * H) + half * 512;
  const float4* xr = (const float4*)x + half * 512;

  float sum = 0.f;
#pragma unroll
  for (int j = 0; j < 8; ++j) {                  // 2048 cols per half
    const float4 a = wr[j * 64 + lane];
    const float4 b = xr[j * 64 + lane];          // L1-resident after first touch
    sum = fmaf(a.x, b.x, sum);
    sum = fmaf(a.y, b.y, sum);
    sum = fmaf(a.z, b.z, sum);
    sum = fmaf(a.w, b.w, sum);
  }
#pragma unroll
  for (int off = 32; off > 0; off >>= 1) sum += __shfl_xor(sum, off);
  if (lane == 0) outp[r] = sum;
}

// ------------- attention: block = (kv head, 32-pos chunk), all 4 q-heads -------------
__global__ __launch_bounds__(256) void attn_split(
    const float* __restrict__ kcache, const float* __restrict__ vcache,
    const float* __restrict__ cosc, const float* __restrict__ sinc,
    const int* __restrict__ curp, float* __restrict__ ws) {
  const int kh    = blockIdx.x;
  const int split = blockIdx.y;
  const int cur   = curp[0];
  const int total = cur + 1;
  const int p0    = split * CHUNK;
  if (p0 >= total) return;

  __shared__ float Ks[CHUNK * KSTR];
  __shared__ float Vs[CHUNK * KSTR];
  __shared__ float q_s[GROUPS * HD];
  __shared__ float es[GROUPS][CHUNK];

  const int t = threadIdx.x;

  // ---- stage K/V chunk into LDS: batched float4 loads, 8 rows/round
  {
    const int r4 = t >> 5;            // 0..7
    const int c4 = (t & 31) * 4;      // float offset within row
    const float* kb = kcache + (size_t)kh * CACHE * HD;
    const float* vb = vcache + (size_t)kh * CACHE * HD;
#pragma unroll
    for (int rr = 0; rr < CHUNK; rr += 8) {
      const int row = rr + r4;
      const int p   = min(p0 + row, cur);      // clamp: rows past cur masked later
      if (p0 + row != cur) {                   // row 'cur' filled from fresh k/v below
        float4 kv = *(const float4*)(kb + (size_t)p * HD + c4);
        float4 vv = *(const float4*)(vb + (size_t)p * HD + c4);
        *(float4*)&Ks[row * KSTR + c4] = kv;
        *(float4*)&Vs[row * KSTR + c4] = vv;
      }
    }
  }
  // ---- RoPE q for this group's 4 heads (512 values, 2/thread); sum split-K halves
#pragma unroll
  for (int i = 0; i < 2; ++i) {
    const int idx = t + i * 256;
    const int qh = idx >> 7, d = idx & 127;
    const int h = kh * GROUPS + qh;
    const float c  = cosc[(size_t)cur * HD + d];
    const float s  = sinc[(size_t)cur * HD + d];
    const float x1 = ws[QOFF + h * HD + d] + ws[QOFF + 4096 + h * HD + d];
    const int d2 = (d < HD / 2) ? d + HD / 2 : d - HD / 2;
    float x2 = ws[QOFF + h * HD + d2] + ws[QOFF + 4096 + h * HD + d2];
    x2 = (d < HD / 2) ? -x2 : x2;
    q_s[qh * HD + d] = x1 * c + x2 * s;
  }
  // ---- fresh k (RoPE'd) / v into row cur-p0 if this chunk contains cur
  if (cur >= p0 && cur < p0 + CHUNK) {
    const int row = cur - p0;
    if (t < HD) {
      const int d = t;
      const float c  = cosc[(size_t)cur * HD + d];
      const float s  = sinc[(size_t)cur * HD + d];
      const float k1 = ws[KOFF + kh * HD + d] + ws[KOFF + 1024 + kh * HD + d];
      const int d2 = (d < HD / 2) ? d + HD / 2 : d - HD / 2;
      float k2 = ws[KOFF + kh * HD + d2] + ws[KOFF + 1024 + kh * HD + d2];
      k2 = (d < HD / 2) ? -k2 : k2;
      Ks[row * KSTR + d] = k1 * c + k2 * s;
    } else if (t < 2 * HD) {
      const int d = t - HD;
      Vs[row * KSTR + d] = ws[VOFF + kh * HD + d] + ws[VOFF + 1024 + kh * HD + d];
    }
  }
  __syncthreads();

  // ---- scores + softmax: thread t<128 owns one (qh, pos); 32-lane group = one qh
  if (t < 128) {
    const int qh = t >> 5, pos = t & 31;
    float4 a = make_float4(0.f, 0.f, 0.f, 0.f);
#pragma unroll
    for (int j = 0; j < HD / 4; ++j) {
      float4 kv = *(const float4*)&Ks[pos * KSTR + j * 4];
      float4 qv = *(const float4*)&q_s[qh * HD + j * 4];
      a.x += kv.x * qv.x; a.y += kv.y * qv.y;
      a.z += kv.z * qv.z; a.w += kv.w * qv.w;
    }
    float s = (a.x + a.y + a.z + a.w) * SCALE;
    const bool valid = (p0 + pos) < total;
    s = valid ? s : -INFINITY;
    float m = s;
#pragma unroll
    for (int off = 16; off > 0; off >>= 1) m = fmaxf(m, __shfl_xor(m, off));
    const float e = valid ? __expf(s - m) : 0.f;
    float l = e;
#pragma unroll
    for (int off = 16; off > 0; off >>= 1) l += __shfl_xor(l, off);
    es[qh][pos] = e;
    if (pos == 0) {
      float* part = ws + POFF + (size_t)((kh * GROUPS + qh) * NSPL + split) * PSTRIDE;
      part[0] = m; part[1] = l;
    }
  }
  __syncthreads();

  // ---- P.V from LDS: thread -> (qh, d-pair), unrolled 32-pos loop
  {
    const int qh = t >> 6;
    const int d0 = (t & 63) * 2;
    float2 acc = make_float2(0.f, 0.f);
#pragma unroll
    for (int pos = 0; pos < CHUNK; ++pos) {
      const float w = es[qh][pos];
      const float2 vv = *(const float2*)&Vs[pos * KSTR + d0];
      acc.x += w * vv.x; acc.y += w * vv.y;
    }
    float* part = ws + POFF + (size_t)((kh * GROUPS + qh) * NSPL + split) * PSTRIDE;
    part[4 + d0]     = acc.x;
    part[4 + d0 + 1] = acc.y;
  }
}

// ---------------- combine splits ----------------
__global__ __launch_bounds__(128) void attn_combine(
    const int* __restrict__ curp, float* __restrict__ ws) {
  const int h = blockIdx.x;
  const int t = threadIdx.x;
  const int total = curp[0] + 1;
  const int nspl = (total + CHUNK - 1) / CHUNK;
  __shared__ float wsh[64];
  __shared__ float Lsh;

  if (t < 64) {
    float mt = -INFINITY, lt = 0.f;
    if (t < nspl) {
      const float* part = ws + POFF + (size_t)(h * NSPL + t) * PSTRIDE;
      mt = part[0]; lt = part[1];
    }
    float M = mt;
#pragma unroll
    for (int off = 32; off > 0; off >>= 1) M = fmaxf(M, __shfl_xor(M, off));
    const float w = (t < nspl) ? __expf(mt - M) : 0.f;
    float lw = lt * w;
#pragma unroll
    for (int off = 32; off > 0; off >>= 1) lw += __shfl_xor(lw, off);
    wsh[t] = w;
    if (t == 0) Lsh = lw;
  }
  __syncthreads();

  const float Linv = 1.f / Lsh;
  float acc = 0.f;
#pragma unroll 8
  for (int i = 0; i < nspl; ++i)
    acc += wsh[i] * ws[POFF + (size_t)(h * NSPL + i) * PSTRIDE + 4 + t];
  ws[CTXOFF + h * HD + t] = acc * Linv;
}

// ---------------- output projection GEMV: no LDS, streaming ----------------
__global__ __launch_bounds__(256, 4) void o_gemv(
    const float* __restrict__ ow, const float* __restrict__ ws,
    float* __restrict__ out) {
  const int t    = threadIdx.x;
  const int wave = t >> 6;
  const int lane = t & 63;
  const int row  = blockIdx.x * 4 + wave;

  const float4* wr = (const float4*)(ow + (size_t)row * H);
  const float4* xr = (const float4*)(ws + CTXOFF);

  float sum = 0.f;
#pragma unroll
  for (int j = 0; j < 16; ++j) {
    const float4 a = wr[j * 64 + lane];
    const float4 b = xr[j * 64 + lane];          // L1/L2-resident ctx
    sum = fmaf(a.x, b.x, sum);
    sum = fmaf(a.y, b.y, sum);
    sum = fmaf(a.z, b.z, sum);
    sum = fmaf(a.w, b.w, sum);
  }
#pragma unroll
  for (int off = 32; off > 0; off >>= 1) sum += __shfl_xor(sum, off);
  if (lane == 0) out[row] = sum;
}

extern "C" void kernel_launch(void* const* d_in, const int* in_sizes, int n_in,
                              void* d_out, int out_size, void* d_ws, size_t ws_size,
                              hipStream_t stream) {
  const float* hs   = (const float*)d_in[0];   // hidden_states (1,1,4096)
  const float* kc   = (const float*)d_in[2];   // (1,8,2048,128)
  const float* vc   = (const float*)d_in[3];
  const float* qw   = (const float*)d_in[4];   // (4096,4096)
  const float* kw   = (const float*)d_in[5];   // (1024,4096)
  const float* vw   = (const float*)d_in[6];   // (1024,4096)
  const float* ow   = (const float*)d_in[7];   // (4096,4096)
  const float* cosc = (const float*)d_in[8];   // (1,4096,128)
  const float* sinc = (const float*)d_in[9];
  const int*   cur  = (const int*)d_in[11];    // current_pos scalar
  float* ws  = (float*)d_ws;
  float* out = (float*)d_out;

  qkv_gemv<<<3072, 256, 0, stream>>>(hs, qw, kw, vw, ws);
  attn_split<<<dim3(NKV, NSPL), 256, 0, stream>>>(kc, vc, cosc, sinc, cur, ws);
  attn_combine<<<NH, 128, 0, stream>>>(cur, ws);
  o_gemv<<<1024, 256, 0, stream>>>(ow, ws, out);
}